// Round 6
// baseline (24.131 us; speedup 1.0000x reference)
//
#include <hip/hip_runtime.h>

// Problem constants (from reference): B=8, N=256, MO=64, D=128
#define PB 8
#define PN 256
#define PMO 64
#define PD 128
#define PV (PD / 4)            // 32 float4 per (b,n,pos) row
#define ROW_V4 (PMO * PV)      // 2048 float4 per (b,n)
#define BLOCK 256
#define ITERS (ROW_V4 / BLOCK) // 8

typedef float f4 __attribute__((ext_vector_type(4)));

__global__ __launch_bounds__(BLOCK)
void combinator_fused_kernel(const float* __restrict__ left_buf,
                             const float* __restrict__ left_count,
                             const float* __restrict__ right_buf,
                             const float* __restrict__ right_count,
                             const int* __restrict__ subs,
                             float* __restrict__ out_buf,
                             float* __restrict__ out_count) {
    int bn = blockIdx.x;                  // flat (b,n), 0..2047 — block-uniform
    int s  = subs[bn];                    // uniform -> scalar load
    float lc = left_count[bn];
    float rc = right_count[bn];
    float fcf = (s == 1) ? rc : lc;
    float scf = (s == 1) ? lc : rc;
    int fc = max((int)rintf(fcf), 0);     // round-half-even == jnp.round
    int sc = max((int)rintf(scf), 0);
    int lim = fc + sc;                    // <= 64 since fc,sc <= 32

    if (threadIdx.x == 0)
        out_count[bn] = fminf(fcf + scf, (float)PMO);

    int base = bn << 11;                  // * ROW_V4
    const f4* first  = (const f4*)((s == 1) ? right_buf : left_buf) + base;
    const f4* second = (const f4*)((s == 1) ? left_buf  : right_buf) + base;
    f4* out = (f4*)out_buf + base;

    int end1 = fc  << 5;                  // v4-units end of first region
    int end2 = lim << 5;                  // v4-units end of second region
    int sc32m1 = max((sc << 5) - 1, 0);   // clamp bound for second-region index

    int tid = (int)threadIdx.x;
    #pragma unroll
    for (int i = 0; i < ITERS; ++i) {
        int idx = tid + (i << 8);                      // 0..2047
        // Branchless: one always-in-bounds load + select.
        int j2 = idx - end1;
        int j2c = max(0, min(j2, sc32m1));             // in [0, sc*32) or 0
        const f4* p = (idx < end1) ? (first + idx) : (second + j2c);
        f4 o = __builtin_nontemporal_load(p);          // streaming read, no reuse
        o = (idx < end2) ? o : (f4)(0.0f);             // zero tail via cndmask
        __builtin_nontemporal_store(o, out + idx);     // streaming write
    }
}

extern "C" void kernel_launch(void* const* d_in, const int* in_sizes, int n_in,
                              void* d_out, int out_size, void* d_ws, size_t ws_size,
                              hipStream_t stream) {
    const float* left_buf    = (const float*)d_in[0];
    const float* left_count  = (const float*)d_in[1];
    const float* right_buf   = (const float*)d_in[2];
    const float* right_count = (const float*)d_in[3];
    const int*   subs        = (const int*)d_in[4];

    float* out_buf   = (float*)d_out;
    float* out_count = out_buf + (long)PB * PN * PMO * PD;

    combinator_fused_kernel<<<PB * PN, BLOCK, 0, stream>>>(
        left_buf, left_count, right_buf, right_count, subs, out_buf, out_count);
}

// Round 7
// 18.648 us; speedup vs baseline: 1.2941x; 1.2941x over previous
//
#include <hip/hip_runtime.h>

// Problem constants (from reference): B=8, N=256, MO=64, D=128
#define PB 8
#define PN 256
#define PMO 64
#define PD 128
#define PV (PD / 4)            // 32 float4 per (b,n,pos) row
#define ROW_V4 (PMO * PV)      // 2048 float4 per (b,n)
#define BLOCK 256
#define ITERS (ROW_V4 / BLOCK) // 8

typedef float f4 __attribute__((ext_vector_type(4)));

// Best measured configuration (round 4, 18.48 us):
//  - one block per (b,n): counts/subs scalar-uniform, count write fused
//  - branchless inner loop: always-in-bounds clamped load + cndmask zero tail
//    (tail's clamped loads are L1 broadcast hits -> plain loads, NOT nontemporal)
//  - nontemporal STORE only: output has no reuse before the harness's 262MB
//    fill dispatches evict L3 between replays (round-5 A/B: plain store +1.1us)
__global__ __launch_bounds__(BLOCK)
void combinator_fused_kernel(const float* __restrict__ left_buf,
                             const float* __restrict__ left_count,
                             const float* __restrict__ right_buf,
                             const float* __restrict__ right_count,
                             const int* __restrict__ subs,
                             float* __restrict__ out_buf,
                             float* __restrict__ out_count) {
    int bn = blockIdx.x;                  // flat (b,n), 0..2047 — block-uniform
    int s  = subs[bn];                    // uniform -> scalar load
    float lc = left_count[bn];
    float rc = right_count[bn];
    float fcf = (s == 1) ? rc : lc;
    float scf = (s == 1) ? lc : rc;
    int fc = max((int)rintf(fcf), 0);     // round-half-even == jnp.round
    int sc = max((int)rintf(scf), 0);
    int lim = fc + sc;                    // <= 64 since fc,sc <= 32

    if (threadIdx.x == 0)
        out_count[bn] = fminf(fcf + scf, (float)PMO);

    int base = bn << 11;                  // * ROW_V4
    const f4* first  = (const f4*)((s == 1) ? right_buf : left_buf) + base;
    const f4* second = (const f4*)((s == 1) ? left_buf  : right_buf) + base;
    f4* out = (f4*)out_buf + base;

    int end1 = fc  << 5;                  // v4-units end of first region
    int end2 = lim << 5;                  // v4-units end of second region
    int sc32m1 = max((sc << 5) - 1, 0);   // clamp bound for second-region index

    int tid = (int)threadIdx.x;
    #pragma unroll
    for (int i = 0; i < ITERS; ++i) {
        int idx = tid + (i << 8);                      // 0..2047
        // Branchless: one always-in-bounds load + select.
        int j2 = idx - end1;
        int j2c = max(0, min(j2, sc32m1));             // in [0, sc*32) or 0
        const f4* p = (idx < end1) ? (first + idx) : (second + j2c);
        f4 o = *p;                                     // plain load (L1-friendly tail)
        o = (idx < end2) ? o : (f4)(0.0f);             // zero tail via cndmask
        __builtin_nontemporal_store(o, out + idx);     // streaming write
    }
}

extern "C" void kernel_launch(void* const* d_in, const int* in_sizes, int n_in,
                              void* d_out, int out_size, void* d_ws, size_t ws_size,
                              hipStream_t stream) {
    const float* left_buf    = (const float*)d_in[0];
    const float* left_count  = (const float*)d_in[1];
    const float* right_buf   = (const float*)d_in[2];
    const float* right_count = (const float*)d_in[3];
    const int*   subs        = (const int*)d_in[4];

    float* out_buf   = (float*)d_out;
    float* out_count = out_buf + (long)PB * PN * PMO * PD;

    combinator_fused_kernel<<<PB * PN, BLOCK, 0, stream>>>(
        left_buf, left_count, right_buf, right_count, subs, out_buf, out_count);
}